// Round 16
// baseline (98.665 us; speedup 1.0000x reference)
//
#include <hip/hip_runtime.h>

// Problem: B=16384, X_DIM=1024, K=64, fp32 in/out.
// out[b] = 0.5 * ( sum_k (x_b . V[:,k])^2  -  sum_i x_bi^2 w_i ),  w_i = sum_k V[i][k]^2
//
// R16 = R15 with the staging BARRIER eliminated (wave-self-contained staging):
//  - wave w's K-loop reads only i in [128w,128w+128) of the block's 16 rows, so
//    each wave DMAs its OWN 16x128-float slice (8 global_load_lds_dwordx4, two
//    512B row-segments per DMA via lane halves) and its own 128-entry w-slice.
//    Per-wave vmcnt dependency replaces __syncthreads: ZERO barriers before the
//    epilogue; waves stagger instead of convoying on the slowest DMA.
//  - bank plan (no swizzle possible): segment = 256 floats + 4-float pad ->
//    A-frag bank base = (4*(m>>1) + 8q) % 32 -> exactly 8 words/bank (b128 floor).
//  - K-loop, repack, z, combine epilogue: identical to R15.

typedef short short8 __attribute__((ext_vector_type(8)));   // 8 bf16 = 4 VGPRs
typedef float f32x4 __attribute__((ext_vector_type(4)));

constexpr int XD = 1024;
constexpr int KD = 64;
constexpr int SEG = 260;            // floats per row-pair segment (256 + 4 pad)
constexpr int WREG = 8 * SEG;       // 2080 floats (8320 B) per-wave region

static __device__ __forceinline__ unsigned short f2bf(float f) {
    union { float f; unsigned u; } v; v.f = f;
    unsigned r = v.u + 0x7FFFu + ((v.u >> 16) & 1u);   // RNE
    return (unsigned short)(r >> 16);
}
static __device__ __forceinline__ unsigned fbits(float f) {
    union { float f; unsigned u; } v; v.f = f; return v.u;
}
static __device__ __forceinline__ void load_lds16(const float* g, float* l) {
    __builtin_amdgcn_global_load_lds(
        (const __attribute__((address_space(1))) unsigned int*)g,
        (__attribute__((address_space(3))) unsigned int*)l,
        16, 0, 0);   // 16 B/lane: global_load_lds_dwordx4
}

// ---- prep: blocks 0..31 build bf16 B-fragments (RNE); 32..35 build w ----
// B-fragment layout (mfma_f32_16x16x32_bf16): lane l holds B[k=(l>>4)*8+j][n=l&15]
// ws: bh @ 0 (131072 B) | wc @ 131072 (4096 B)
__global__ void prep_kernel(const float* __restrict__ v,
                            unsigned short* __restrict__ bh,
                            float* __restrict__ wc) {
    if (blockIdx.x < 32) {
        int idx = blockIdx.x * 256 + threadIdx.x;
        int it = idx >> 8;
        int r  = idx & 255;
        int t  = r >> 6;
        int l  = r & 63;
        int q  = l >> 4, m = l & 15;
        int base_i = it * 32 + q * 8;
        int n = t * 16 + m;
        size_t fo = ((size_t)(it * 4 + t) * 64 + l) * 8;
#pragma unroll
        for (int j = 0; j < 8; ++j) {
            float val = v[(size_t)(base_i + j) * KD + n];
            bh[fo + j] = f2bf(val);
        }
    } else {
        int i = (blockIdx.x - 32) * 256 + threadIdx.x;   // 0..1023
        const f32x4* vp = (const f32x4*)(v + (size_t)i * KD);
        f32x4 tv[16];
#pragma unroll
        for (int qq = 0; qq < 16; ++qq) tv[qq] = vp[qq];
        float s = 0.f;
#pragma unroll
        for (int qq = 0; qq < 16; ++qq) {
            s = fmaf(tv[qq].x, tv[qq].x, s); s = fmaf(tv[qq].y, tv[qq].y, s);
            s = fmaf(tv[qq].z, tv[qq].z, s); s = fmaf(tv[qq].w, tv[qq].w, s);
        }
        wc[i] = s;
    }
}

// ---- main: 512 thr / 8 waves; block = 16 rows; wave = self-staged 128-i slice ----
__global__ __launch_bounds__(512, 4)
void cross_r16(const float* __restrict__ x,
               const unsigned short* __restrict__ bh,
               const float* __restrict__ wc,
               float* __restrict__ out) {
    // xbuf: 8 per-wave regions x 2080 floats = 66,560 B (DMA-staged, pad-banked).
    // After the epilogue barrier the front is reused as the combine area.
    __shared__ __align__(16) float xbuf[8 * WREG];
    __shared__ float wl[8][128];       // per-wave w-slice, 4 KB (broadcast reads)
    __shared__ float zb[7][16];        //  448 B   (total ~71 KB -> 2 blocks/CU)

    const int tid = threadIdx.x;
    const int l = tid & 63;
    const int w = __builtin_amdgcn_readfirstlane(tid >> 6);   // wave 0..7
    const int q = l >> 4, m = l & 15;
    const int row0 = blockIdx.x * 16;

    // ---- per-wave staging: NO barrier. 8 DMAs cover 16 rows x 128 floats ----
    // DMA j: lanes 0..31 -> row 2j, lanes 32..63 -> row 2j+1 (512 B each, coalesced)
    float* wreg = &xbuf[w * WREG];
#pragma unroll
    for (int j = 0; j < 8; ++j) {
        const float* g = x + (size_t)(row0 + 2 * j + (l >> 5)) * XD
                           + w * 128 + (l & 31) * 4;
        load_lds16(g, &wreg[j * SEG]);   // wave-uniform base; HW adds lane*16
    }
    // per-wave w-slice (2 floats/lane, coalesced)
    *(float2*)&wl[w][l * 2] = *(const float2*)(wc + w * 128 + l * 2);

    // ---- compute: 4 local i-tiles; compiler inserts vmcnt wait before first read ----
    f32x4 c4[4];
#pragma unroll
    for (int t = 0; t < 4; ++t) c4[t] = f32x4{0.f, 0.f, 0.f, 0.f};
    float z = 0.f;

    const short8* bhp = (const short8*)bh;

#pragma unroll
    for (int itl = 0; itl < 4; ++itl) {
        const int it = w * 4 + itl;
        const size_t fbase = (size_t)(it * 4) * 64 + l;

        // A source: row m -> seg m>>1, half m&1; bank base = (4*(m>>1)+8q)%32
        const int base = (m >> 1) * SEG + (m & 1) * 128 + itl * 32 + q * 8;
        f32x4 xa = *(const f32x4*)&wreg[base];
        f32x4 xb = *(const f32x4*)&wreg[base + 4];

        const float* wp = &wl[w][itl * 32 + q * 8];
        f32x4 wa = *(const f32x4*)wp, wb = *(const f32x4*)(wp + 4);
        float xs[8] = {xa.x, xa.y, xa.z, xa.w, xb.x, xb.y, xb.z, xb.w};
        z = fmaf(xs[0]*xs[0], wa.x, z); z = fmaf(xs[1]*xs[1], wa.y, z);
        z = fmaf(xs[2]*xs[2], wa.z, z); z = fmaf(xs[3]*xs[3], wa.w, z);
        z = fmaf(xs[4]*xs[4], wb.x, z); z = fmaf(xs[5]*xs[5], wb.y, z);
        z = fmaf(xs[6]*xs[6], wb.z, z); z = fmaf(xs[7]*xs[7], wb.w, z);

        // RNE bf16 pack of x (pairwise via v_perm)
        unsigned ahp[4];
#pragma unroll
        for (int jp = 0; jp < 4; ++jp) {
            unsigned u0 = fbits(xs[2 * jp]);
            unsigned u1 = fbits(xs[2 * jp + 1]);
            u0 += 0x7FFFu + ((u0 >> 16) & 1u);
            u1 += 0x7FFFu + ((u1 >> 16) & 1u);
            ahp[jp] = __builtin_amdgcn_perm(u1, u0, 0x07060302u);  // {hi16(u1),hi16(u0)}
        }
        short8 ah;
#pragma unroll
        for (int jp = 0; jp < 4; ++jp) {
            ah[2*jp]   = (short)(ahp[jp] & 0xFFFF);
            ah[2*jp+1] = (short)(ahp[jp] >> 16);
        }

        // 4 independent MFMA chains (one per col-tile t)
#pragma unroll
        for (int t = 0; t < 4; ++t) {
            short8 vh = bhp[fbase + (size_t)t * 64];
            c4[t] = __builtin_amdgcn_mfma_f32_16x16x32_bf16(ah, vh, c4[t], 0, 0, 0);
        }
    }

    // z: sum over q-chunks -> full-q partial z for row m (this wave's i-range)
    z += __shfl_xor(z, 16);
    z += __shfl_xor(z, 32);

    __syncthreads();   // first and only pre-combine barrier; xbuf reuse is safe after
    float* comb = xbuf;   // 7 slots x 64 lanes x 17 floats = 7616 <= 16640

    if (w > 0) {
        const int s = w - 1;
#pragma unroll
        for (int t = 0; t < 4; ++t)
#pragma unroll
            for (int r = 0; r < 4; ++r) comb[(s * 64 + l) * 17 + t * 4 + r] = c4[t][r];
        if (l < 16) zb[s][l] = z;
    }
    __syncthreads();

    if (w == 0) {
#pragma unroll
        for (int s = 0; s < 7; ++s) {
#pragma unroll
            for (int t = 0; t < 4; ++t)
#pragma unroll
                for (int r = 0; r < 4; ++r) c4[t][r] += comb[(s * 64 + l) * 17 + t * 4 + r];
            z += zb[s][m];
        }

        // C layout: col = l&15, row = q*4 + reg
        float p[4] = {0.f, 0.f, 0.f, 0.f};
#pragma unroll
        for (int r = 0; r < 4; ++r)
#pragma unroll
            for (int t = 0; t < 4; ++t) p[r] = fmaf(c4[t][r], c4[t][r], p[r]);
#pragma unroll
        for (int mask = 1; mask < 16; mask <<= 1)
#pragma unroll
            for (int r = 0; r < 4; ++r) p[r] += __shfl_xor(p[r], mask);

        float zrow = __shfl(z, q * 4 + m, 16);
        if (m < 4) out[row0 + q * 4 + m] = 0.5f * (p[m] - zrow);
    }
}

extern "C" void kernel_launch(void* const* d_in, const int* in_sizes, int n_in,
                              void* d_out, int out_size, void* d_ws, size_t ws_size,
                              hipStream_t stream) {
    const float* x = (const float*)d_in[0];      // (16384, 1024) fp32
    const float* v = (const float*)d_in[1];      // (1024, 64) fp32
    float* out = (float*)d_out;                  // (16384, 1) fp32

    unsigned short* bh = (unsigned short*)d_ws;                    // 131072 B
    float* wc = (float*)((char*)d_ws + 131072);                    //   4096 B

    const int B = in_sizes[0] / XD;              // 16384

    hipLaunchKernelGGL(prep_kernel, dim3(36), dim3(256), 0, stream, v, bh, wc);
    hipLaunchKernelGGL(cross_r16, dim3(B / 16), dim3(512), 0, stream,
                       x, bh, wc, out);
}